// Round 5
// baseline (480.082 us; speedup 1.0000x reference)
//
#include <hip/hip_runtime.h>
#include <hip/hip_bf16.h>

#define NC 100000
#define NU 100000
#define NE 1600000
#define DC 256
#define DU 128
#define HID 128
#define OUTD 64

#define TM 32                                // GEMM tile rows (NC, NU divisible)
#define NT_C (NC / TM)                       // 3125
#define NT_U (NU / TM)                       // 3125
#define NHB 256                              // hist blocks fused ahead of GEMM blocks

#define SH (HID + 8)                         // h_s row stride (shorts)

#define SCAN_TILE 16384                      // scan_off tile (64 KB LDS)

typedef __attribute__((ext_vector_type(8))) short bf16x8;
typedef __attribute__((ext_vector_type(4))) float f32x4;

// RNE float->bf16 (finite inputs)
__device__ inline unsigned short f2b(float f) {
    unsigned int u = __float_as_uint(f);
    u += 0x7fffu + ((u >> 16) & 1u);
    return (unsigned short)(u >> 16);
}

// ---------------------------------------------------------------------------
// K0: Wlo_p = packed (Wl@Wo) bf16, Wro_p = packed (Wr@Wo) bf16, b2 = bl@Wo+bo.
// 4x K-split + LDS reduce. Packed B-fragment layout for GEMM2 (16x16x32 mfma):
//   element W2[k][f]: idx = ((w*4 + ks)*64 + quad*16 + l16)*8 + e
//   with f = w*16+l16, k = ks*32 + quad*8 + e.
// ---------------------------------------------------------------------------
__global__ void prep_kernel(const float* __restrict__ Wl, const float* __restrict__ bl,
                            const float* __restrict__ Wr, const float* __restrict__ Wo,
                            const float* __restrict__ bo,
                            __hip_bfloat16* __restrict__ Wlo_p,
                            __hip_bfloat16* __restrict__ Wro_p,
                            float* __restrict__ b2) {
    const int k = blockIdx.x;          // 0..127 (HID)
    const int t = threadIdx.x;         // 0..255
    const int f = t & 63, j4 = t >> 6; // f: out col, j4: K-slice
    __shared__ float red[3][4][OUTD];
    float a0 = 0.f, a1 = 0.f, s = 0.f;
    for (int m = j4 * 32; m < j4 * 32 + 32; ++m) {
        float wo = Wo[m * OUTD + f];
        a0 = fmaf(Wl[k * HID + m], wo, a0);
        a1 = fmaf(Wr[k * HID + m], wo, a1);
        s = fmaf(bl[m], wo, s);
    }
    red[0][j4][f] = a0; red[1][j4][f] = a1; red[2][j4][f] = s;
    __syncthreads();
    if (j4 == 0) {
        a0 = red[0][0][f] + red[0][1][f] + red[0][2][f] + red[0][3][f];
        a1 = red[1][0][f] + red[1][1][f] + red[1][2][f] + red[1][3][f];
        const int wv = f >> 4, l16 = f & 15;
        const int ks = k >> 5, quad = (k >> 3) & 3, e = k & 7;
        const int idx = (((wv * 4 + ks) * 64) + quad * 16 + l16) * 8 + e;
        Wlo_p[idx] = __float2bfloat16(a0);
        Wro_p[idx] = __float2bfloat16(a1);
        if (k == 0)
            b2[f] = bo[f] + red[2][0][f] + red[2][1][f] + red[2][2][f] + red[2][3][f];
    }
}

// ---------------------------------------------------------------------------
// K0b: pack input-proj weight W[K][HID] into GEMM1 B-fragment-linear layout:
//   element W[k][j]: idx = (((j>>4)*(K/32) + (k>>5))*64 + ((k>>3)&3)*16 + (j&15))*8 + (k&7)
// ---------------------------------------------------------------------------
__global__ void pack_w(const float* __restrict__ W, __hip_bfloat16* __restrict__ Wp,
                       int K) {
    int i = blockIdx.x * blockDim.x + threadIdx.x;
    int total = K * HID;
    if (i >= total) return;
    int j = i % HID, k = i / HID;
    int nks = K >> 5;
    int idx = (((j >> 4) * nks + (k >> 5)) * 64 + ((k >> 3) & 3) * 16 + (j & 15)) * 8 +
              (k & 7);
    Wp[idx] = __float2bfloat16(W[k * HID + j]);
}

// ---------------------------------------------------------------------------
// Device GEMM path (unchanged from R4): p = relu(x @ W1 + b1) @ W2 (+bias2)
// ---------------------------------------------------------------------------
template <int DIN, bool BF16OUT>
__device__ __forceinline__ void gemm_path(const float* __restrict__ x,
                                          const __hip_bfloat16* __restrict__ W1p,
                                          const float* __restrict__ b1,
                                          const __hip_bfloat16* __restrict__ W2p,
                                          const float* __restrict__ bias2,
                                          void* __restrict__ outp, int tile,
                                          short* __restrict__ smem) {
    constexpr int NKS = DIN / 32;        // GEMM1 K-steps
    constexpr int SA = DIN + 8;          // A row stride (shorts): +16B pad
    constexpr int CPR = DIN / 8;         // 8-float chunks per row
    constexpr int RSTEP = 256 / CPR;     // rows per 256-thread sweep
    constexpr int NCH = TM / RSTEP;      // sweeps (4 content / 2 user)
    short* a_s = smem;                   // [TM][SA]
    short* h_s = smem + TM * SA;         // [TM][SH]

    const int t = threadIdx.x;
    const int w = t >> 6, lane = t & 63;
    const int quad = lane >> 4, l16 = lane & 15;
    const int r0 = t / CPR, c0 = t % CPR;
    const int base = tile * TM;

    // ---- B fragments (packed, coalesced, L2-hot) ----
    bf16x8 b1f[2][NKS];
#pragma unroll
    for (int ntl = 0; ntl < 2; ++ntl)
#pragma unroll
        for (int ks = 0; ks < NKS; ++ks)
            b1f[ntl][ks] =
                *(const bf16x8*)&W1p[(size_t)(((2 * w + ntl) * NKS + ks) * 64 + lane) * 8];
    bf16x8 b2f[HID / 32];
#pragma unroll
    for (int ks = 0; ks < HID / 32; ++ks)
        b2f[ks] = *(const bf16x8*)&W2p[(size_t)((w * 4 + ks) * 64 + lane) * 8];
    const float bb1_0 = b1[w * 32 + l16];
    const float bb1_1 = b1[w * 32 + 16 + l16];
    const float bb2 = BF16OUT ? 0.f : bias2[w * 16 + l16];

    // ---- stage A tile: coalesced fp32 loads -> f2b -> ds_write_b128 ----
    float4 va[NCH][2];
#pragma unroll
    for (int k = 0; k < NCH; ++k) {
        const float4* p = (const float4*)(x + (size_t)(base + r0 + k * RSTEP) * DIN + c0 * 8);
        va[k][0] = p[0];
        va[k][1] = p[1];
    }
#pragma unroll
    for (int k = 0; k < NCH; ++k) {
        bf16x8 a;
        a[0] = (short)f2b(va[k][0].x); a[1] = (short)f2b(va[k][0].y);
        a[2] = (short)f2b(va[k][0].z); a[3] = (short)f2b(va[k][0].w);
        a[4] = (short)f2b(va[k][1].x); a[5] = (short)f2b(va[k][1].y);
        a[6] = (short)f2b(va[k][1].z); a[7] = (short)f2b(va[k][1].w);
        *(bf16x8*)&a_s[(r0 + k * RSTEP) * SA + c0 * 8] = a;
    }
    __syncthreads();

    // ---- GEMM1: h = relu(x @ W1 + b1), wave w -> cols [32w, 32w+32) ----
#pragma unroll
    for (int rg = 0; rg < TM / 16; ++rg) {
        bf16x8 af[NKS];
#pragma unroll
        for (int ks = 0; ks < NKS; ++ks)
            af[ks] = *(const bf16x8*)&a_s[(rg * 16 + l16) * SA + ks * 32 + quad * 8];
        f32x4 acc0 = (f32x4){0.f, 0.f, 0.f, 0.f};
        f32x4 acc1 = (f32x4){0.f, 0.f, 0.f, 0.f};
#pragma unroll
        for (int ks = 0; ks < NKS; ++ks) {
            acc0 = __builtin_amdgcn_mfma_f32_16x16x32_bf16(af[ks], b1f[0][ks], acc0, 0, 0, 0);
            acc1 = __builtin_amdgcn_mfma_f32_16x16x32_bf16(af[ks], b1f[1][ks], acc1, 0, 0, 0);
        }
#pragma unroll
        for (int r = 0; r < 4; ++r) {
            int row = rg * 16 + quad * 4 + r;
            h_s[row * SH + w * 32 + l16] = (short)f2b(fmaxf(acc0[r] + bb1_0, 0.f));
            h_s[row * SH + w * 32 + 16 + l16] = (short)f2b(fmaxf(acc1[r] + bb1_1, 0.f));
        }
    }
    __syncthreads();

    // ---- GEMM2: p = h @ W2 (+bias2), wave w -> out cols [16w, 16w+16) ----
#pragma unroll
    for (int rg = 0; rg < TM / 16; ++rg) {
        f32x4 acc = (f32x4){0.f, 0.f, 0.f, 0.f};
#pragma unroll
        for (int ks = 0; ks < HID / 32; ++ks) {
            bf16x8 a = *(const bf16x8*)&h_s[(rg * 16 + l16) * SH + ks * 32 + quad * 8];
            acc = __builtin_amdgcn_mfma_f32_16x16x32_bf16(a, b2f[ks], acc, 0, 0, 0);
        }
#pragma unroll
        for (int r = 0; r < 4; ++r) {
            int rr = base + rg * 16 + quad * 4 + r;
            if (BF16OUT)
                ((unsigned short*)outp)[(size_t)rr * OUTD + w * 16 + l16] = f2b(acc[r]);
            else
                ((float*)outp)[(size_t)rr * OUTD + w * 16 + l16] = acc[r] + bb2;
        }
    }
}

// ---------------------------------------------------------------------------
// Fused kernel: blocks [0,NHB) = edge histogram (global atomics, rides in the
// GEMM's latency bubbles); [NHB, NHB+NT_C) = content GEMM; rest = user GEMM.
// ---------------------------------------------------------------------------
__global__ void __launch_bounds__(256, 4) fused_gemm_hist(
    const float* __restrict__ xc, const __hip_bfloat16* __restrict__ Wc_p,
    const float* __restrict__ bc, const __hip_bfloat16* __restrict__ Wro_p,
    const float* __restrict__ b2, float* __restrict__ out,
    const float* __restrict__ xu, const __hip_bfloat16* __restrict__ Wu_p,
    const float* __restrict__ bu, const __hip_bfloat16* __restrict__ Wlo_p,
    unsigned short* __restrict__ pu,
    const int* __restrict__ edst, int* __restrict__ cnt) {
    __shared__ __align__(16) short smem[TM * (DC + 8) + TM * (HID + 8)];
    int b = blockIdx.x;
    if (b < NHB) {
        int i = b * 256 + threadIdx.x;
        for (; i < NE; i += NHB * 256) atomicAdd(&cnt[edst[i]], 1);
        return;
    }
    b -= NHB;
    if (b < NT_C)
        gemm_path<DC, false>(xc, Wc_p, bc, Wro_p, b2, out, b, smem);
    else
        gemm_path<DU, true>(xu, Wu_p, bu, Wlo_p, nullptr, pu, b - NT_C, smem);
}

// ---------------------------------------------------------------------------
// Single-block exclusive scan of cnt[NC] -> off[], cur[] (and off[NC]=NE).
// 1024 threads; per-tile: 16-elem serial scan + wave shfl_up scan + 16-wave
// combine. 4 barriers per 16K tile, 7 tiles.
// ---------------------------------------------------------------------------
__global__ void __launch_bounds__(1024) scan_off(const int* __restrict__ cnt,
                                                 int* __restrict__ off,
                                                 int* __restrict__ cur) {
    __shared__ int tile[SCAN_TILE];   // 64 KB
    __shared__ int wsum[16];
    __shared__ int wbase[16];
    __shared__ int carry;
    const int t = threadIdx.x;
    const int lane = t & 63, wv = t >> 6;
    if (t == 0) carry = 0;
    __syncthreads();
    for (int t0 = 0; t0 < NC; t0 += SCAN_TILE) {
        const int n = min(SCAN_TILE, NC - t0);
        for (int i = t; i < n; i += 1024) tile[i] = cnt[t0 + i];
        __syncthreads();
        const int b0 = t * 16;
        int s = 0;
        if (b0 < n) {
            int m = min(16, n - b0);
#pragma unroll
            for (int j = 0; j < 16; ++j)
                if (j < m) { int v = tile[b0 + j]; tile[b0 + j] = s; s += v; }
        }
        int inc = s;
#pragma unroll
        for (int d = 1; d < 64; d <<= 1) {
            int x = __shfl_up(inc, d, 64);
            if (lane >= d) inc += x;
        }
        if (lane == 63) wsum[wv] = inc;
        __syncthreads();
        if (t == 0) {
            int r = 0;
            for (int i = 0; i < 16; ++i) { int v = wsum[i]; wbase[i] = r; r += v; }
            wsum[0] = r;   // tile total (wbase already derived)
        }
        __syncthreads();
        const int base = carry + wbase[wv] + (inc - s);
        if (b0 < n) {
            int m = min(16, n - b0);
#pragma unroll
            for (int j = 0; j < 16; ++j)
                if (j < m) {
                    int v = base + tile[b0 + j];
                    off[t0 + b0 + j] = v;
                    cur[t0 + b0 + j] = v;
                }
        }
        __syncthreads();
        if (t == 0) carry += wsum[0];
        __syncthreads();
    }
    if (t == 0) off[NC] = NE;
}

// ---------------------------------------------------------------------------
// Scatter: one pass, global atomics on cur[] -> ssrc grouped by dst.
// ---------------------------------------------------------------------------
__global__ void __launch_bounds__(256) scatter_edges(const int* __restrict__ src,
                                                     const int* __restrict__ dst,
                                                     int* __restrict__ cur,
                                                     int* __restrict__ ssrc) {
    int i = blockIdx.x * 256 + threadIdx.x;
    const int stride = gridDim.x * 256;
    for (; i < NE; i += stride) {
        int d = dst[i];
        int p = atomicAdd(&cur[d], 1);
        ssrc[p] = src[i];
    }
}

// ---------------------------------------------------------------------------
// Gather-aggregate (bf16 pu) + mean + add into out. One wave per node.
// 2x-unrolled edge loop: two random pu-row loads in flight per lane-group.
// ---------------------------------------------------------------------------
__global__ void __launch_bounds__(256) gather_agg(const int* __restrict__ ssrc,
                                                  const int* __restrict__ off,
                                                  const unsigned int* __restrict__ pu,
                                                  float* __restrict__ out) {
    int node = blockIdx.x * 4 + (threadIdx.x >> 6);
    if (node >= NC) return;
    int lane = threadIdx.x & 63;
    int g = lane >> 3;
    int f8 = lane & 7;
    int e0 = off[node], e1 = off[node + 1];
    const uint4* pu4 = (const uint4*)pu;
    float acc[8] = {0.f, 0.f, 0.f, 0.f, 0.f, 0.f, 0.f, 0.f};
    int e = e0 + g;
    for (; e + 8 < e1; e += 16) {
        int s0 = ssrc[e];
        int s1 = ssrc[e + 8];
        uint4 v0 = pu4[(size_t)s0 * 8 + f8];
        uint4 v1 = pu4[(size_t)s1 * 8 + f8];
        acc[0] += __uint_as_float(v0.x << 16);
        acc[1] += __uint_as_float(v0.x & 0xffff0000u);
        acc[2] += __uint_as_float(v0.y << 16);
        acc[3] += __uint_as_float(v0.y & 0xffff0000u);
        acc[4] += __uint_as_float(v0.z << 16);
        acc[5] += __uint_as_float(v0.z & 0xffff0000u);
        acc[6] += __uint_as_float(v0.w << 16);
        acc[7] += __uint_as_float(v0.w & 0xffff0000u);
        acc[0] += __uint_as_float(v1.x << 16);
        acc[1] += __uint_as_float(v1.x & 0xffff0000u);
        acc[2] += __uint_as_float(v1.y << 16);
        acc[3] += __uint_as_float(v1.y & 0xffff0000u);
        acc[4] += __uint_as_float(v1.z << 16);
        acc[5] += __uint_as_float(v1.z & 0xffff0000u);
        acc[6] += __uint_as_float(v1.w << 16);
        acc[7] += __uint_as_float(v1.w & 0xffff0000u);
    }
    if (e < e1) {
        int s = ssrc[e];
        uint4 v = pu4[(size_t)s * 8 + f8];
        acc[0] += __uint_as_float(v.x << 16);
        acc[1] += __uint_as_float(v.x & 0xffff0000u);
        acc[2] += __uint_as_float(v.y << 16);
        acc[3] += __uint_as_float(v.y & 0xffff0000u);
        acc[4] += __uint_as_float(v.z << 16);
        acc[5] += __uint_as_float(v.z & 0xffff0000u);
        acc[6] += __uint_as_float(v.w << 16);
        acc[7] += __uint_as_float(v.w & 0xffff0000u);
    }
#pragma unroll
    for (int m = 8; m <= 32; m <<= 1) {
#pragma unroll
        for (int j = 0; j < 8; ++j) acc[j] += __shfl_xor(acc[j], m, 64);
    }
    if (g == 0) {
        float inv = 1.0f / (float)max(e1 - e0, 1);
        float4* po = (float4*)(out + (size_t)node * OUTD + f8 * 8);
        float4 o0 = po[0], o1 = po[1];
        o0.x += acc[0] * inv; o0.y += acc[1] * inv;
        o0.z += acc[2] * inv; o0.w += acc[3] * inv;
        o1.x += acc[4] * inv; o1.y += acc[5] * inv;
        o1.z += acc[6] * inv; o1.w += acc[7] * inv;
        po[0] = o0; po[1] = o1;
    }
}

extern "C" void kernel_launch(void* const* d_in, const int* in_sizes, int n_in,
                              void* d_out, int out_size, void* d_ws, size_t ws_size,
                              hipStream_t stream) {
    const float* xc = (const float*)d_in[0];
    const float* xu = (const float*)d_in[1];
    const int*   ei = (const int*)d_in[2];
    const float* Wc = (const float*)d_in[3];
    const float* bc = (const float*)d_in[4];
    const float* Wu = (const float*)d_in[5];
    const float* bu = (const float*)d_in[6];
    const float* Wl = (const float*)d_in[7];
    const float* bl = (const float*)d_in[8];
    const float* Wr = (const float*)d_in[9];
    const float* Wo = (const float*)d_in[10];
    const float* bo = (const float*)d_in[11];
    float* out = (float*)d_out;

    const int* esrc = ei;        // edge_index[0] = user ids
    const int* edst = ei + NE;   // edge_index[1] = content ids

    // workspace carve (all chunk sizes multiples of 16 B)
    unsigned short* pu = (unsigned short*)d_ws;             // NU*64 bf16 (12.8 MB)
    int* ssrc = (int*)(pu + (size_t)NU * OUTD);             // NE (6.4 MB)
    int* cnt  = ssrc + NE;                                  // NC (400 KB)
    int* cur  = cnt + NC;                                   // NC (400 KB)
    int* off  = cur + NC;                                   // NC+1 (pad to NC+4)
    float* b2 = (float*)(off + NC + 4);                     // 64
    __hip_bfloat16* Wlo_p = (__hip_bfloat16*)(b2 + OUTD);   // 64*128
    __hip_bfloat16* Wro_p = Wlo_p + OUTD * HID;             // 64*128
    __hip_bfloat16* Wu_p  = Wro_p + OUTD * HID;             // 128*128
    __hip_bfloat16* Wc_p  = Wu_p + HID * DU;                // 128*256

    hipMemsetAsync(cnt, 0, NC * sizeof(int), stream);

    prep_kernel<<<HID, 256, 0, stream>>>(Wl, bl, Wr, Wo, bo, Wlo_p, Wro_p, b2);
    pack_w<<<(DU * HID + 255) / 256, 256, 0, stream>>>(Wu, Wu_p, DU);
    pack_w<<<(DC * HID + 255) / 256, 256, 0, stream>>>(Wc, Wc_p, DC);

    fused_gemm_hist<<<NHB + NT_C + NT_U, 256, 0, stream>>>(
        xc, Wc_p, bc, Wro_p, b2, out, xu, Wu_p, bu, Wlo_p, pu, edst, cnt);

    scan_off<<<1, 1024, 0, stream>>>(cnt, off, cur);
    scatter_edges<<<2048, 256, 0, stream>>>(esrc, edst, cur, ssrc);
    gather_agg<<<(NC + 3) / 4, 256, 0, stream>>>(ssrc, off, (const unsigned int*)pu, out);
}

// Round 6
// 365.901 us; speedup vs baseline: 1.3121x; 1.3121x over previous
//
#include <hip/hip_runtime.h>
#include <hip/hip_bf16.h>

#define NC 100000
#define NU 100000
#define NE 1600000
#define DC 256
#define DU 128
#define HID 128
#define OUTD 64

#define BSHIFT 7
#define BRANGE 128
#define NBUCK ((NC + BRANGE - 1) / BRANGE)   // 782
#define BCAP 4096                            // Poisson(2048) -> huge margin
#define EPB 4096
#define NBA ((NE + EPB - 1) / EPB)           // 391

#define TM 32                                // GEMM tile rows (NC, NU divisible)
#define NT_C (NC / TM)                       // 3125
#define NT_U (NU / TM)                       // 3125

#define SH (HID + 8)                         // h_s row stride (shorts)

// fused_main LDS: max(bucket_a 29920, gemm 25600)
#define SMEM_FUSED 29920

typedef __attribute__((ext_vector_type(8))) short bf16x8;
typedef __attribute__((ext_vector_type(4))) float f32x4;

// RNE float->bf16 (finite inputs)
__device__ inline unsigned short f2b(float f) {
    unsigned int u = __float_as_uint(f);
    u += 0x7fffu + ((u >> 16) & 1u);
    return (unsigned short)(u >> 16);
}

// ---------------------------------------------------------------------------
// prep_all: ONE launch for all weight prep.
//  blocks [0,HID):    Wlo_p/Wro_p/b2 (4x K-split + LDS reduce)
//  blocks [HID,320):  pack Wu then Wc into B-fragment-linear layout;
//                     block HID also zeros gcur.
// Packed B-fragment layout (16x16x32 mfma), W[K][HID] element (k,j):
//   idx = (((j>>4)*(K/32) + (k>>5))*64 + ((k>>3)&3)*16 + (j&15))*8 + (k&7)
// ---------------------------------------------------------------------------
__global__ void __launch_bounds__(256) prep_all(
    const float* __restrict__ Wl, const float* __restrict__ bl,
    const float* __restrict__ Wr, const float* __restrict__ Wo,
    const float* __restrict__ bo, const float* __restrict__ Wu,
    const float* __restrict__ Wc, __hip_bfloat16* __restrict__ Wlo_p,
    __hip_bfloat16* __restrict__ Wro_p, float* __restrict__ b2,
    __hip_bfloat16* __restrict__ Wu_p, __hip_bfloat16* __restrict__ Wc_p,
    int* __restrict__ gcur) {
    __shared__ float red[3][4][OUTD];
    const int b = blockIdx.x;
    const int t = threadIdx.x;
    if (b < HID) {
        const int k = b;
        const int f = t & 63, j4 = t >> 6;
        float a0 = 0.f, a1 = 0.f, s = 0.f;
        for (int m = j4 * 32; m < j4 * 32 + 32; ++m) {
            float wo = Wo[m * OUTD + f];
            a0 = fmaf(Wl[k * HID + m], wo, a0);
            a1 = fmaf(Wr[k * HID + m], wo, a1);
            s = fmaf(bl[m], wo, s);
        }
        red[0][j4][f] = a0; red[1][j4][f] = a1; red[2][j4][f] = s;
        __syncthreads();
        if (j4 == 0) {
            a0 = red[0][0][f] + red[0][1][f] + red[0][2][f] + red[0][3][f];
            a1 = red[1][0][f] + red[1][1][f] + red[1][2][f] + red[1][3][f];
            const int wv = f >> 4, l16 = f & 15;
            const int ks = k >> 5, quad = (k >> 3) & 3, e = k & 7;
            const int idx = (((wv * 4 + ks) * 64) + quad * 16 + l16) * 8 + e;
            Wlo_p[idx] = __float2bfloat16(a0);
            Wro_p[idx] = __float2bfloat16(a1);
            if (k == 0)
                b2[f] = bo[f] + red[2][0][f] + red[2][1][f] + red[2][2][f] + red[2][3][f];
        }
        return;
    }
    if (b == HID)
        for (int j = t; j < NBUCK; j += 256) gcur[j] = 0;
    int i = (b - HID) * 256 + t;
    if (i < DU * HID) {
        int j = i % HID, k = i / HID;
        int idx = (((j >> 4) * (DU / 32) + (k >> 5)) * 64 + ((k >> 3) & 3) * 16 +
                   (j & 15)) * 8 + (k & 7);
        Wu_p[idx] = __float2bfloat16(Wu[k * HID + j]);
    } else {
        int i2 = i - DU * HID;
        if (i2 < DC * HID) {
            int j = i2 % HID, k = i2 / HID;
            int idx = (((j >> 4) * (DC / 32) + (k >> 5)) * 64 + ((k >> 3) & 3) * 16 +
                       (j & 15)) * 8 + (k & 7);
            Wc_p[idx] = __float2bfloat16(Wc[k * HID + j]);
        }
    }
}

// ---------------------------------------------------------------------------
// Device GEMM path (unchanged from R4): p = relu(x @ W1 + b1) @ W2 (+bias2)
// ---------------------------------------------------------------------------
template <int DIN, bool BF16OUT>
__device__ __forceinline__ void gemm_path(const float* __restrict__ x,
                                          const __hip_bfloat16* __restrict__ W1p,
                                          const float* __restrict__ b1,
                                          const __hip_bfloat16* __restrict__ W2p,
                                          const float* __restrict__ bias2,
                                          void* __restrict__ outp, int tile,
                                          short* __restrict__ smem) {
    constexpr int NKS = DIN / 32;
    constexpr int SA = DIN + 8;
    constexpr int CPR = DIN / 8;
    constexpr int RSTEP = 256 / CPR;
    constexpr int NCH = TM / RSTEP;
    short* a_s = smem;                   // [TM][SA]
    short* h_s = smem + TM * SA;         // [TM][SH]

    const int t = threadIdx.x;
    const int w = t >> 6, lane = t & 63;
    const int quad = lane >> 4, l16 = lane & 15;
    const int r0 = t / CPR, c0 = t % CPR;
    const int base = tile * TM;

    bf16x8 b1f[2][NKS];
#pragma unroll
    for (int ntl = 0; ntl < 2; ++ntl)
#pragma unroll
        for (int ks = 0; ks < NKS; ++ks)
            b1f[ntl][ks] =
                *(const bf16x8*)&W1p[(size_t)(((2 * w + ntl) * NKS + ks) * 64 + lane) * 8];
    bf16x8 b2f[HID / 32];
#pragma unroll
    for (int ks = 0; ks < HID / 32; ++ks)
        b2f[ks] = *(const bf16x8*)&W2p[(size_t)((w * 4 + ks) * 64 + lane) * 8];
    const float bb1_0 = b1[w * 32 + l16];
    const float bb1_1 = b1[w * 32 + 16 + l16];
    const float bb2 = BF16OUT ? 0.f : bias2[w * 16 + l16];

    float4 va[NCH][2];
#pragma unroll
    for (int k = 0; k < NCH; ++k) {
        const float4* p = (const float4*)(x + (size_t)(base + r0 + k * RSTEP) * DIN + c0 * 8);
        va[k][0] = p[0];
        va[k][1] = p[1];
    }
#pragma unroll
    for (int k = 0; k < NCH; ++k) {
        bf16x8 a;
        a[0] = (short)f2b(va[k][0].x); a[1] = (short)f2b(va[k][0].y);
        a[2] = (short)f2b(va[k][0].z); a[3] = (short)f2b(va[k][0].w);
        a[4] = (short)f2b(va[k][1].x); a[5] = (short)f2b(va[k][1].y);
        a[6] = (short)f2b(va[k][1].z); a[7] = (short)f2b(va[k][1].w);
        *(bf16x8*)&a_s[(r0 + k * RSTEP) * SA + c0 * 8] = a;
    }
    __syncthreads();

#pragma unroll
    for (int rg = 0; rg < TM / 16; ++rg) {
        bf16x8 af[NKS];
#pragma unroll
        for (int ks = 0; ks < NKS; ++ks)
            af[ks] = *(const bf16x8*)&a_s[(rg * 16 + l16) * SA + ks * 32 + quad * 8];
        f32x4 acc0 = (f32x4){0.f, 0.f, 0.f, 0.f};
        f32x4 acc1 = (f32x4){0.f, 0.f, 0.f, 0.f};
#pragma unroll
        for (int ks = 0; ks < NKS; ++ks) {
            acc0 = __builtin_amdgcn_mfma_f32_16x16x32_bf16(af[ks], b1f[0][ks], acc0, 0, 0, 0);
            acc1 = __builtin_amdgcn_mfma_f32_16x16x32_bf16(af[ks], b1f[1][ks], acc1, 0, 0, 0);
        }
#pragma unroll
        for (int r = 0; r < 4; ++r) {
            int row = rg * 16 + quad * 4 + r;
            h_s[row * SH + w * 32 + l16] = (short)f2b(fmaxf(acc0[r] + bb1_0, 0.f));
            h_s[row * SH + w * 32 + 16 + l16] = (short)f2b(fmaxf(acc1[r] + bb1_1, 0.f));
        }
    }
    __syncthreads();

#pragma unroll
    for (int rg = 0; rg < TM / 16; ++rg) {
        f32x4 acc = (f32x4){0.f, 0.f, 0.f, 0.f};
#pragma unroll
        for (int ks = 0; ks < HID / 32; ++ks) {
            bf16x8 a = *(const bf16x8*)&h_s[(rg * 16 + l16) * SH + ks * 32 + quad * 8];
            acc = __builtin_amdgcn_mfma_f32_16x16x32_bf16(a, b2f[ks], acc, 0, 0, 0);
        }
#pragma unroll
        for (int r = 0; r < 4; ++r) {
            int rr = base + rg * 16 + quad * 4 + r;
            if (BF16OUT)
                ((unsigned short*)outp)[(size_t)rr * OUTD + w * 16 + l16] = f2b(acc[r]);
            else
                ((float*)outp)[(size_t)rr * OUTD + w * 16 + l16] = acc[r] + bb2;
        }
    }
}

// ---------------------------------------------------------------------------
// bucket_a path (device fn): LDS-bucketed scatter of EPB edges into NBUCK
// buckets; per-bucket slab positions from atomicAdd(gcur[b]) -> bke slabs are
// self-contained (no global scan needed downstream).
// LDS: pk 16K + 4*NBUCK*4 (12.5K) + ts 1K = 29920 B
// ---------------------------------------------------------------------------
__device__ void bucket_a_path(const int* __restrict__ src, const int* __restrict__ dst,
                              int* __restrict__ gcur, unsigned int* __restrict__ bke,
                              int blk, char* __restrict__ sm) {
    unsigned int* pk = (unsigned int*)sm;            // [EPB]
    int* hist  = (int*)(sm + EPB * 4);               // [NBUCK]
    int* lbase = hist + NBUCK;
    int* lcur  = lbase + NBUCK;
    int* gb    = lcur + NBUCK;
    int* ts    = gb + NBUCK;                         // [256]
    const int t = threadIdx.x;
    const int base = blk * EPB;

    for (int i = t; i < NBUCK; i += 256) hist[i] = 0;
    __syncthreads();
#pragma unroll
    for (int k = 0; k < EPB / 256; ++k) {
        int e = base + k * 256 + t;
        if (e < NE) atomicAdd(&hist[dst[e] >> BSHIFT], 1);
    }
    __syncthreads();
    // exclusive scan over NBUCK: thread t owns [4t, 4t+4)
    int h[4];
    int s = 0;
#pragma unroll
    for (int j = 0; j < 4; ++j) {
        int idx = 4 * t + j;
        h[j] = (idx < NBUCK) ? hist[idx] : 0;
        s += h[j];
    }
    ts[t] = s;
    __syncthreads();
    for (int d = 1; d < 256; d <<= 1) {
        int x = (t >= d) ? ts[t - d] : 0;
        __syncthreads();
        ts[t] += x;
        __syncthreads();
    }
    int ex = ts[t] - s;
#pragma unroll
    for (int j = 0; j < 4; ++j) {
        int idx = 4 * t + j;
        if (idx < NBUCK) {
            lbase[idx] = ex;
            lcur[idx] = ex;
            if (h[j] > 0) gb[idx] = atomicAdd(&gcur[idx], h[j]);
            ex += h[j];
        }
    }
    __syncthreads();
#pragma unroll
    for (int k = 0; k < EPB / 256; ++k) {
        int e = base + k * 256 + t;
        if (e < NE) {
            int sv = src[e], d = dst[e];
            int bb = d >> BSHIFT;
            int p = atomicAdd(&lcur[bb], 1);
            pk[p] = ((unsigned int)sv << BSHIFT) | (unsigned int)(d & (BRANGE - 1));
        }
    }
    __syncthreads();
    const int wv = t >> 6, ln = t & 63;
    for (int bb = wv; bb < NBUCK; bb += 4) {
        int s0 = lbase[bb], c = hist[bb], g0 = gb[bb];
        for (int j = ln; j < c; j += 64) {
            int pos = g0 + j;
            if (pos < BCAP) bke[(size_t)bb * BCAP + pos] = pk[s0 + j];
        }
    }
}

// ---------------------------------------------------------------------------
// fused_main: blocks [0,NBA) = bucket_a; [NBA,NBA+NT_C) = content GEMM;
// rest = user GEMM. bucket_a's integer/LDS work rides in GEMM idle pipes.
// ---------------------------------------------------------------------------
__global__ void __launch_bounds__(256, 4) fused_main(
    const float* __restrict__ xc, const __hip_bfloat16* __restrict__ Wc_p,
    const float* __restrict__ bc, const __hip_bfloat16* __restrict__ Wro_p,
    const float* __restrict__ b2, float* __restrict__ out,
    const float* __restrict__ xu, const __hip_bfloat16* __restrict__ Wu_p,
    const float* __restrict__ bu, const __hip_bfloat16* __restrict__ Wlo_p,
    unsigned short* __restrict__ pu,
    const int* __restrict__ esrc, const int* __restrict__ edst,
    int* __restrict__ gcur, unsigned int* __restrict__ bke) {
    __shared__ __align__(16) char smem[SMEM_FUSED];
    int b = blockIdx.x;
    if (b < NBA) {
        bucket_a_path(esrc, edst, gcur, bke, b, smem);
        return;
    }
    b -= NBA;
    if (b < NT_C)
        gemm_path<DC, false>(xc, Wc_p, bc, Wro_p, b2, out, b, (short*)smem);
    else
        gemm_path<DU, true>(xu, Wu_p, bu, Wlo_p, nullptr, pu, b - NT_C, (short*)smem);
}

// ---------------------------------------------------------------------------
// bucket_gather: per bucket (128 nodes, ~2048 edges): load slab, LDS counting
// sort by local node, then aggregate pu rows directly from sorted LDS list
// into out (mean + add). Replaces scan_mid + bucket_b + gather_agg; no global
// ssrc/off round-trip.
// ---------------------------------------------------------------------------
__global__ void __launch_bounds__(256) bucket_gather(
    const int* __restrict__ gcur, const unsigned int* __restrict__ bke,
    const unsigned int* __restrict__ pu, float* __restrict__ out) {
    __shared__ unsigned int pk[BCAP];    // 16 KB
    __shared__ int sl[BCAP];             // 16 KB (srcs sorted by local node)
    __shared__ int hist[BRANGE];
    __shared__ int hb[BRANGE + 1];
    __shared__ int cur[BRANGE];
    __shared__ int ts[256];
    const int t = threadIdx.x;
    const int b = blockIdx.x;
    const int n = min(gcur[b], BCAP);

    for (int i = t; i < n; i += 256) pk[i] = bke[(size_t)b * BCAP + i];
    if (t < BRANGE) hist[t] = 0;
    __syncthreads();
    for (int i = t; i < n; i += 256) atomicAdd(&hist[pk[i] & (BRANGE - 1)], 1);
    __syncthreads();
    int h = (t < BRANGE) ? hist[t] : 0;
    ts[t] = h;
    __syncthreads();
    for (int d = 1; d < 256; d <<= 1) {
        int x = (t >= d) ? ts[t - d] : 0;
        __syncthreads();
        ts[t] += x;
        __syncthreads();
    }
    if (t < BRANGE) {
        hb[t] = ts[t] - h;
        cur[t] = ts[t] - h;
    }
    if (t == 0) hb[BRANGE] = n;
    __syncthreads();
    for (int i = t; i < n; i += 256) {
        unsigned int v = pk[i];
        int p = atomicAdd(&cur[v & (BRANGE - 1)], 1);
        sl[p] = (int)(v >> BSHIFT);
    }
    __syncthreads();

    // ---- aggregate: wave wv handles local nodes wv, wv+4, ... ----
    const int wv = t >> 6, lane = t & 63;
    const int g = lane >> 3, f8 = lane & 7;
    const int node0 = b * BRANGE;
    const int nn = min(BRANGE, NC - node0);
    const uint4* pu4 = (const uint4*)pu;
    for (int i = wv; i < nn; i += 4) {
        const int e0 = hb[i], e1 = hb[i + 1];
        float acc[8] = {0.f, 0.f, 0.f, 0.f, 0.f, 0.f, 0.f, 0.f};
        int e = e0 + g;
        for (; e + 8 < e1; e += 16) {
            int s0 = sl[e];
            int s1 = sl[e + 8];
            uint4 v0 = pu4[(size_t)s0 * 8 + f8];
            uint4 v1 = pu4[(size_t)s1 * 8 + f8];
            acc[0] += __uint_as_float(v0.x << 16);
            acc[1] += __uint_as_float(v0.x & 0xffff0000u);
            acc[2] += __uint_as_float(v0.y << 16);
            acc[3] += __uint_as_float(v0.y & 0xffff0000u);
            acc[4] += __uint_as_float(v0.z << 16);
            acc[5] += __uint_as_float(v0.z & 0xffff0000u);
            acc[6] += __uint_as_float(v0.w << 16);
            acc[7] += __uint_as_float(v0.w & 0xffff0000u);
            acc[0] += __uint_as_float(v1.x << 16);
            acc[1] += __uint_as_float(v1.x & 0xffff0000u);
            acc[2] += __uint_as_float(v1.y << 16);
            acc[3] += __uint_as_float(v1.y & 0xffff0000u);
            acc[4] += __uint_as_float(v1.z << 16);
            acc[5] += __uint_as_float(v1.z & 0xffff0000u);
            acc[6] += __uint_as_float(v1.w << 16);
            acc[7] += __uint_as_float(v1.w & 0xffff0000u);
        }
        if (e < e1) {
            int s = sl[e];
            uint4 v = pu4[(size_t)s * 8 + f8];
            acc[0] += __uint_as_float(v.x << 16);
            acc[1] += __uint_as_float(v.x & 0xffff0000u);
            acc[2] += __uint_as_float(v.y << 16);
            acc[3] += __uint_as_float(v.y & 0xffff0000u);
            acc[4] += __uint_as_float(v.z << 16);
            acc[5] += __uint_as_float(v.z & 0xffff0000u);
            acc[6] += __uint_as_float(v.w << 16);
            acc[7] += __uint_as_float(v.w & 0xffff0000u);
        }
#pragma unroll
        for (int m = 8; m <= 32; m <<= 1) {
#pragma unroll
            for (int j = 0; j < 8; ++j) acc[j] += __shfl_xor(acc[j], m, 64);
        }
        if (g == 0) {
            float inv = 1.0f / (float)max(e1 - e0, 1);
            float4* po = (float4*)(out + (size_t)(node0 + i) * OUTD + f8 * 8);
            float4 o0 = po[0], o1 = po[1];
            o0.x += acc[0] * inv; o0.y += acc[1] * inv;
            o0.z += acc[2] * inv; o0.w += acc[3] * inv;
            o1.x += acc[4] * inv; o1.y += acc[5] * inv;
            o1.z += acc[6] * inv; o1.w += acc[7] * inv;
            po[0] = o0; po[1] = o1;
        }
    }
}

extern "C" void kernel_launch(void* const* d_in, const int* in_sizes, int n_in,
                              void* d_out, int out_size, void* d_ws, size_t ws_size,
                              hipStream_t stream) {
    const float* xc = (const float*)d_in[0];
    const float* xu = (const float*)d_in[1];
    const int*   ei = (const int*)d_in[2];
    const float* Wc = (const float*)d_in[3];
    const float* bc = (const float*)d_in[4];
    const float* Wu = (const float*)d_in[5];
    const float* bu = (const float*)d_in[6];
    const float* Wl = (const float*)d_in[7];
    const float* bl = (const float*)d_in[8];
    const float* Wr = (const float*)d_in[9];
    const float* Wo = (const float*)d_in[10];
    const float* bo = (const float*)d_in[11];
    float* out = (float*)d_out;

    const int* esrc = ei;        // edge_index[0] = user ids
    const int* edst = ei + NE;   // edge_index[1] = content ids

    // workspace carve (all chunk sizes multiples of 16 B)
    unsigned short* pu = (unsigned short*)d_ws;             // NU*64 bf16 (12.8 MB)
    unsigned int* bke = (unsigned int*)(pu + (size_t)NU * OUTD); // NBUCK*BCAP (12.8 MB)
    int* gcur = (int*)(bke + (size_t)NBUCK * BCAP);         // 782 (pad to 784)
    float* b2 = (float*)(gcur + 784);                       // 64
    __hip_bfloat16* Wlo_p = (__hip_bfloat16*)(b2 + OUTD);   // 64*128
    __hip_bfloat16* Wro_p = Wlo_p + OUTD * HID;             // 64*128
    __hip_bfloat16* Wu_p  = Wro_p + OUTD * HID;             // 128*128
    __hip_bfloat16* Wc_p  = Wu_p + HID * DU;                // 128*256

    prep_all<<<HID + (DU * HID + DC * HID) / 256, 256, 0, stream>>>(
        Wl, bl, Wr, Wo, bo, Wu, Wc, Wlo_p, Wro_p, b2, Wu_p, Wc_p, gcur);

    fused_main<<<NBA + NT_C + NT_U, 256, 0, stream>>>(
        xc, Wc_p, bc, Wro_p, b2, out, xu, Wu_p, bu, Wlo_p, pu, esrc, edst, gcur, bke);

    bucket_gather<<<NBUCK, 256, 0, stream>>>(gcur, bke, (const unsigned int*)pu, out);
}

// Round 7
// 321.500 us; speedup vs baseline: 1.4933x; 1.1381x over previous
//
#include <hip/hip_runtime.h>
#include <hip/hip_bf16.h>

#define NC 100000
#define NU 100000
#define NE 1600000
#define DC 256
#define DU 128
#define HID 128
#define OUTD 64

#define BSHIFT 9
#define BRANGE 512
#define NBUCK ((NC + BRANGE - 1) / BRANGE)   // 196
#define BCAP 10240                           // slab cap; mean fill 8163, 23 sigma
#define EPB 8192
#define NBA ((NE + EPB - 1) / EPB)           // 196 bucket blocks

#define TM 32                                // GEMM tile rows (NC, NU divisible)
#define NT_C (NC / TM)                       // 3125
#define NT_U (NU / TM)                       // 3125

#define SH (HID + 8)                         // h_s row stride (shorts)

// fused_main LDS: bucket_a needs 32768(pk)+4*196*4(hist/lbase/lcur/gb)+1024(ts)
//               = 36928 B > gemm 25600 B. 160K/36.9K = 4 blocks/CU preserved.
#define SMEM_FUSED 36928

typedef __attribute__((ext_vector_type(8))) short bf16x8;
typedef __attribute__((ext_vector_type(4))) float f32x4;

// RNE float->bf16 (finite inputs)
__device__ inline unsigned short f2b(float f) {
    unsigned int u = __float_as_uint(f);
    u += 0x7fffu + ((u >> 16) & 1u);
    return (unsigned short)(u >> 16);
}

// ---------------------------------------------------------------------------
// prep_all: ONE launch for all weight prep (proven in R6).
//  blocks [0,HID):    Wlo_p/Wro_p/b2 (4x K-split + LDS reduce)
//  blocks [HID,320):  pack Wu then Wc into B-fragment-linear layout;
//                     block HID also zeros gcur.
// Packed B-fragment layout (16x16x32 mfma), W[K][HID] element (k,j):
//   idx = (((j>>4)*(K/32) + (k>>5))*64 + ((k>>3)&3)*16 + (j&15))*8 + (k&7)
// ---------------------------------------------------------------------------
__global__ void __launch_bounds__(256) prep_all(
    const float* __restrict__ Wl, const float* __restrict__ bl,
    const float* __restrict__ Wr, const float* __restrict__ Wo,
    const float* __restrict__ bo, const float* __restrict__ Wu,
    const float* __restrict__ Wc, __hip_bfloat16* __restrict__ Wlo_p,
    __hip_bfloat16* __restrict__ Wro_p, float* __restrict__ b2,
    __hip_bfloat16* __restrict__ Wu_p, __hip_bfloat16* __restrict__ Wc_p,
    int* __restrict__ gcur) {
    __shared__ float red[3][4][OUTD];
    const int b = blockIdx.x;
    const int t = threadIdx.x;
    if (b < HID) {
        const int k = b;
        const int f = t & 63, j4 = t >> 6;
        float a0 = 0.f, a1 = 0.f, s = 0.f;
        for (int m = j4 * 32; m < j4 * 32 + 32; ++m) {
            float wo = Wo[m * OUTD + f];
            a0 = fmaf(Wl[k * HID + m], wo, a0);
            a1 = fmaf(Wr[k * HID + m], wo, a1);
            s = fmaf(bl[m], wo, s);
        }
        red[0][j4][f] = a0; red[1][j4][f] = a1; red[2][j4][f] = s;
        __syncthreads();
        if (j4 == 0) {
            a0 = red[0][0][f] + red[0][1][f] + red[0][2][f] + red[0][3][f];
            a1 = red[1][0][f] + red[1][1][f] + red[1][2][f] + red[1][3][f];
            const int wv = f >> 4, l16 = f & 15;
            const int ks = k >> 5, quad = (k >> 3) & 3, e = k & 7;
            const int idx = (((wv * 4 + ks) * 64) + quad * 16 + l16) * 8 + e;
            Wlo_p[idx] = __float2bfloat16(a0);
            Wro_p[idx] = __float2bfloat16(a1);
            if (k == 0)
                b2[f] = bo[f] + red[2][0][f] + red[2][1][f] + red[2][2][f] + red[2][3][f];
        }
        return;
    }
    if (b == HID)
        for (int j = t; j < NBUCK; j += 256) gcur[j] = 0;
    int i = (b - HID) * 256 + t;
    if (i < DU * HID) {
        int j = i % HID, k = i / HID;
        int idx = (((j >> 4) * (DU / 32) + (k >> 5)) * 64 + ((k >> 3) & 3) * 16 +
                   (j & 15)) * 8 + (k & 7);
        Wu_p[idx] = __float2bfloat16(Wu[k * HID + j]);
    } else {
        int i2 = i - DU * HID;
        if (i2 < DC * HID) {
            int j = i2 % HID, k = i2 / HID;
            int idx = (((j >> 4) * (DC / 32) + (k >> 5)) * 64 + ((k >> 3) & 3) * 16 +
                       (j & 15)) * 8 + (k & 7);
            Wc_p[idx] = __float2bfloat16(Wc[k * HID + j]);
        }
    }
}

// ---------------------------------------------------------------------------
// Device GEMM path (unchanged from R4): p = relu(x @ W1 + b1) @ W2 (+bias2)
// ---------------------------------------------------------------------------
template <int DIN, bool BF16OUT>
__device__ __forceinline__ void gemm_path(const float* __restrict__ x,
                                          const __hip_bfloat16* __restrict__ W1p,
                                          const float* __restrict__ b1,
                                          const __hip_bfloat16* __restrict__ W2p,
                                          const float* __restrict__ bias2,
                                          void* __restrict__ outp, int tile,
                                          short* __restrict__ smem) {
    constexpr int NKS = DIN / 32;
    constexpr int SA = DIN + 8;
    constexpr int CPR = DIN / 8;
    constexpr int RSTEP = 256 / CPR;
    constexpr int NCH = TM / RSTEP;
    short* a_s = smem;                   // [TM][SA]
    short* h_s = smem + TM * SA;         // [TM][SH]

    const int t = threadIdx.x;
    const int w = t >> 6, lane = t & 63;
    const int quad = lane >> 4, l16 = lane & 15;
    const int r0 = t / CPR, c0 = t % CPR;
    const int base = tile * TM;

    bf16x8 b1f[2][NKS];
#pragma unroll
    for (int ntl = 0; ntl < 2; ++ntl)
#pragma unroll
        for (int ks = 0; ks < NKS; ++ks)
            b1f[ntl][ks] =
                *(const bf16x8*)&W1p[(size_t)(((2 * w + ntl) * NKS + ks) * 64 + lane) * 8];
    bf16x8 b2f[HID / 32];
#pragma unroll
    for (int ks = 0; ks < HID / 32; ++ks)
        b2f[ks] = *(const bf16x8*)&W2p[(size_t)((w * 4 + ks) * 64 + lane) * 8];
    const float bb1_0 = b1[w * 32 + l16];
    const float bb1_1 = b1[w * 32 + 16 + l16];
    const float bb2 = BF16OUT ? 0.f : bias2[w * 16 + l16];

    float4 va[NCH][2];
#pragma unroll
    for (int k = 0; k < NCH; ++k) {
        const float4* p = (const float4*)(x + (size_t)(base + r0 + k * RSTEP) * DIN + c0 * 8);
        va[k][0] = p[0];
        va[k][1] = p[1];
    }
#pragma unroll
    for (int k = 0; k < NCH; ++k) {
        bf16x8 a;
        a[0] = (short)f2b(va[k][0].x); a[1] = (short)f2b(va[k][0].y);
        a[2] = (short)f2b(va[k][0].z); a[3] = (short)f2b(va[k][0].w);
        a[4] = (short)f2b(va[k][1].x); a[5] = (short)f2b(va[k][1].y);
        a[6] = (short)f2b(va[k][1].z); a[7] = (short)f2b(va[k][1].w);
        *(bf16x8*)&a_s[(r0 + k * RSTEP) * SA + c0 * 8] = a;
    }
    __syncthreads();

#pragma unroll
    for (int rg = 0; rg < TM / 16; ++rg) {
        bf16x8 af[NKS];
#pragma unroll
        for (int ks = 0; ks < NKS; ++ks)
            af[ks] = *(const bf16x8*)&a_s[(rg * 16 + l16) * SA + ks * 32 + quad * 8];
        f32x4 acc0 = (f32x4){0.f, 0.f, 0.f, 0.f};
        f32x4 acc1 = (f32x4){0.f, 0.f, 0.f, 0.f};
#pragma unroll
        for (int ks = 0; ks < NKS; ++ks) {
            acc0 = __builtin_amdgcn_mfma_f32_16x16x32_bf16(af[ks], b1f[0][ks], acc0, 0, 0, 0);
            acc1 = __builtin_amdgcn_mfma_f32_16x16x32_bf16(af[ks], b1f[1][ks], acc1, 0, 0, 0);
        }
#pragma unroll
        for (int r = 0; r < 4; ++r) {
            int row = rg * 16 + quad * 4 + r;
            h_s[row * SH + w * 32 + l16] = (short)f2b(fmaxf(acc0[r] + bb1_0, 0.f));
            h_s[row * SH + w * 32 + 16 + l16] = (short)f2b(fmaxf(acc1[r] + bb1_1, 0.f));
        }
    }
    __syncthreads();

#pragma unroll
    for (int rg = 0; rg < TM / 16; ++rg) {
        f32x4 acc = (f32x4){0.f, 0.f, 0.f, 0.f};
#pragma unroll
        for (int ks = 0; ks < HID / 32; ++ks) {
            bf16x8 a = *(const bf16x8*)&h_s[(rg * 16 + l16) * SH + ks * 32 + quad * 8];
            acc = __builtin_amdgcn_mfma_f32_16x16x32_bf16(a, b2f[ks], acc, 0, 0, 0);
        }
#pragma unroll
        for (int r = 0; r < 4; ++r) {
            int rr = base + rg * 16 + quad * 4 + r;
            if (BF16OUT)
                ((unsigned short*)outp)[(size_t)rr * OUTD + w * 16 + l16] = f2b(acc[r]);
            else
                ((float*)outp)[(size_t)rr * OUTD + w * 16 + l16] = acc[r] + bb2;
        }
    }
}

// ---------------------------------------------------------------------------
// bucket_a path (R4-proven geometry: EPB 8192, BRANGE 512, NBUCK 196).
// Slab positions from atomicAdd(gcur[b]) -> self-contained slabs, no scan
// kernel needed downstream.
// ---------------------------------------------------------------------------
__device__ void bucket_a_path(const int* __restrict__ src, const int* __restrict__ dst,
                              int* __restrict__ gcur, unsigned int* __restrict__ bke,
                              int blk, char* __restrict__ sm) {
    unsigned int* pk = (unsigned int*)sm;            // [EPB] 32 KB
    int* hist  = (int*)(sm + EPB * 4);               // [NBUCK]
    int* lbase = hist + NBUCK;
    int* lcur  = lbase + NBUCK;
    int* gb    = lcur + NBUCK;
    int* ts    = gb + NBUCK;                         // [256]
    const int t = threadIdx.x;
    const int base = blk * EPB;

    for (int i = t; i < NBUCK; i += 256) hist[i] = 0;
    __syncthreads();
#pragma unroll
    for (int k = 0; k < EPB / 256; ++k) {
        int e = base + k * 256 + t;
        if (e < NE) atomicAdd(&hist[dst[e] >> BSHIFT], 1);
    }
    __syncthreads();
    int h = (t < NBUCK) ? hist[t] : 0;
    ts[t] = h;
    __syncthreads();
    for (int d = 1; d < 256; d <<= 1) {
        int x = (t >= d) ? ts[t - d] : 0;
        __syncthreads();
        ts[t] += x;
        __syncthreads();
    }
    if (t < NBUCK) {
        int ex = ts[t] - h;
        lbase[t] = ex;
        lcur[t] = ex;
        gb[t] = (h > 0) ? atomicAdd(&gcur[t], h) : 0;
    }
    __syncthreads();
#pragma unroll
    for (int k = 0; k < EPB / 256; ++k) {
        int e = base + k * 256 + t;
        if (e < NE) {
            int sv = src[e], d = dst[e];
            int bb = d >> BSHIFT;
            int p = atomicAdd(&lcur[bb], 1);
            pk[p] = ((unsigned int)sv << BSHIFT) | (unsigned int)(d & (BRANGE - 1));
        }
    }
    __syncthreads();
    const int wv = t >> 6, ln = t & 63;
    for (int bb = wv; bb < NBUCK; bb += 4) {
        int s0 = lbase[bb], c = hist[bb], g0 = gb[bb];
        for (int j = ln; j < c; j += 64) {
            int pos = g0 + j;
            if (pos < BCAP) bke[(size_t)bb * BCAP + pos] = pk[s0 + j];
        }
    }
}

// ---------------------------------------------------------------------------
// fused_main: blocks [0,NBA) = bucket_a (rides in GEMM idle pipes, 3% of
// grid); [NBA,NBA+NT_C) = content GEMM; rest = user GEMM.
// ---------------------------------------------------------------------------
__global__ void __launch_bounds__(256, 4) fused_main(
    const float* __restrict__ xc, const __hip_bfloat16* __restrict__ Wc_p,
    const float* __restrict__ bc, const __hip_bfloat16* __restrict__ Wro_p,
    const float* __restrict__ b2, float* __restrict__ out,
    const float* __restrict__ xu, const __hip_bfloat16* __restrict__ Wu_p,
    const float* __restrict__ bu, const __hip_bfloat16* __restrict__ Wlo_p,
    unsigned short* __restrict__ pu,
    const int* __restrict__ esrc, const int* __restrict__ edst,
    int* __restrict__ gcur, unsigned int* __restrict__ bke) {
    __shared__ __align__(16) char smem[SMEM_FUSED];
    int b = blockIdx.x;
    if (b < NBA) {
        bucket_a_path(esrc, edst, gcur, bke, b, smem);
        return;
    }
    b -= NBA;
    if (b < NT_C)
        gemm_path<DC, false>(xc, Wc_p, bc, Wro_p, b2, out, b, (short*)smem);
    else
        gemm_path<DU, true>(xu, Wu_p, bu, Wlo_p, nullptr, pu, b - NT_C, (short*)smem);
}

// ---------------------------------------------------------------------------
// bucket_gather (1024 threads): per 512-node bucket, load its slab, LDS
// counting sort by local node, then 16 waves aggregate pu rows per node
// (mean + add into out). Replaces scan_mid + bucket_b + gather_agg; no
// global ssrc/off round-trip.
// LDS: pk 40K + sl 40K + hist 2K + hb 2K+4 + cur 2K + ts 4K = ~92 KB.
// ---------------------------------------------------------------------------
__global__ void __launch_bounds__(1024) bucket_gather(
    const int* __restrict__ gcur, const unsigned int* __restrict__ bke,
    const unsigned int* __restrict__ pu, float* __restrict__ out) {
    __shared__ unsigned int pk[BCAP];
    __shared__ int sl[BCAP];
    __shared__ int hist[BRANGE];
    __shared__ int hb[BRANGE + 1];
    __shared__ int cur[BRANGE];
    __shared__ int ts[1024];
    const int t = threadIdx.x;
    const int b = blockIdx.x;
    const int n = min(gcur[b], BCAP);

    for (int i = t; i < n; i += 1024) pk[i] = bke[(size_t)b * BCAP + i];
    if (t < BRANGE) hist[t] = 0;
    __syncthreads();
    for (int i = t; i < n; i += 1024) atomicAdd(&hist[pk[i] & (BRANGE - 1)], 1);
    __syncthreads();
    int h = (t < BRANGE) ? hist[t] : 0;
    ts[t] = h;
    __syncthreads();
    for (int d = 1; d < BRANGE; d <<= 1) {
        int x = (t >= d) ? ts[t - d] : 0;
        __syncthreads();
        ts[t] += x;
        __syncthreads();
    }
    if (t < BRANGE) {
        hb[t] = ts[t] - h;
        cur[t] = ts[t] - h;
    }
    if (t == 0) hb[BRANGE] = n;
    __syncthreads();
    for (int i = t; i < n; i += 1024) {
        unsigned int v = pk[i];
        int p = atomicAdd(&cur[v & (BRANGE - 1)], 1);
        sl[p] = (int)(v >> BSHIFT);
    }
    __syncthreads();

    // ---- aggregate: wave wv handles local nodes wv, wv+16, ... ----
    const int wv = t >> 6, lane = t & 63;
    const int g = lane >> 3, f8 = lane & 7;
    const int node0 = b * BRANGE;
    const int nn = min(BRANGE, NC - node0);
    const uint4* pu4 = (const uint4*)pu;
    for (int i = wv; i < nn; i += 16) {
        const int e0 = hb[i], e1 = hb[i + 1];
        if (e0 == e1) continue;
        float acc[8] = {0.f, 0.f, 0.f, 0.f, 0.f, 0.f, 0.f, 0.f};
        int e = e0 + g;
        for (; e + 8 < e1; e += 16) {
            int s0 = sl[e];
            int s1 = sl[e + 8];
            uint4 v0 = pu4[(size_t)s0 * 8 + f8];
            uint4 v1 = pu4[(size_t)s1 * 8 + f8];
            acc[0] += __uint_as_float(v0.x << 16);
            acc[1] += __uint_as_float(v0.x & 0xffff0000u);
            acc[2] += __uint_as_float(v0.y << 16);
            acc[3] += __uint_as_float(v0.y & 0xffff0000u);
            acc[4] += __uint_as_float(v0.z << 16);
            acc[5] += __uint_as_float(v0.z & 0xffff0000u);
            acc[6] += __uint_as_float(v0.w << 16);
            acc[7] += __uint_as_float(v0.w & 0xffff0000u);
            acc[0] += __uint_as_float(v1.x << 16);
            acc[1] += __uint_as_float(v1.x & 0xffff0000u);
            acc[2] += __uint_as_float(v1.y << 16);
            acc[3] += __uint_as_float(v1.y & 0xffff0000u);
            acc[4] += __uint_as_float(v1.z << 16);
            acc[5] += __uint_as_float(v1.z & 0xffff0000u);
            acc[6] += __uint_as_float(v1.w << 16);
            acc[7] += __uint_as_float(v1.w & 0xffff0000u);
        }
        if (e < e1) {
            int s = sl[e];
            uint4 v = pu4[(size_t)s * 8 + f8];
            acc[0] += __uint_as_float(v.x << 16);
            acc[1] += __uint_as_float(v.x & 0xffff0000u);
            acc[2] += __uint_as_float(v.y << 16);
            acc[3] += __uint_as_float(v.y & 0xffff0000u);
            acc[4] += __uint_as_float(v.z << 16);
            acc[5] += __uint_as_float(v.z & 0xffff0000u);
            acc[6] += __uint_as_float(v.w << 16);
            acc[7] += __uint_as_float(v.w & 0xffff0000u);
        }
#pragma unroll
        for (int m = 8; m <= 32; m <<= 1) {
#pragma unroll
            for (int j = 0; j < 8; ++j) acc[j] += __shfl_xor(acc[j], m, 64);
        }
        if (g == 0) {
            float inv = 1.0f / (float)(e1 - e0);
            float4* po = (float4*)(out + (size_t)(node0 + i) * OUTD + f8 * 8);
            float4 o0 = po[0], o1 = po[1];
            o0.x += acc[0] * inv; o0.y += acc[1] * inv;
            o0.z += acc[2] * inv; o0.w += acc[3] * inv;
            o1.x += acc[4] * inv; o1.y += acc[5] * inv;
            o1.z += acc[6] * inv; o1.w += acc[7] * inv;
            po[0] = o0; po[1] = o1;
        }
    }
}

extern "C" void kernel_launch(void* const* d_in, const int* in_sizes, int n_in,
                              void* d_out, int out_size, void* d_ws, size_t ws_size,
                              hipStream_t stream) {
    const float* xc = (const float*)d_in[0];
    const float* xu = (const float*)d_in[1];
    const int*   ei = (const int*)d_in[2];
    const float* Wc = (const float*)d_in[3];
    const float* bc = (const float*)d_in[4];
    const float* Wu = (const float*)d_in[5];
    const float* bu = (const float*)d_in[6];
    const float* Wl = (const float*)d_in[7];
    const float* bl = (const float*)d_in[8];
    const float* Wr = (const float*)d_in[9];
    const float* Wo = (const float*)d_in[10];
    const float* bo = (const float*)d_in[11];
    float* out = (float*)d_out;

    const int* esrc = ei;        // edge_index[0] = user ids
    const int* edst = ei + NE;   // edge_index[1] = content ids

    // workspace carve (all chunk sizes multiples of 16 B)
    unsigned short* pu = (unsigned short*)d_ws;             // NU*64 bf16 (12.8 MB)
    unsigned int* bke = (unsigned int*)(pu + (size_t)NU * OUTD); // NBUCK*BCAP (8.03 MB)
    int* gcur = (int*)(bke + (size_t)NBUCK * BCAP);         // 196 (pad to 208)
    float* b2 = (float*)(gcur + 208);                       // 64
    __hip_bfloat16* Wlo_p = (__hip_bfloat16*)(b2 + OUTD);   // 64*128
    __hip_bfloat16* Wro_p = Wlo_p + OUTD * HID;             // 64*128
    __hip_bfloat16* Wu_p  = Wro_p + OUTD * HID;             // 128*128
    __hip_bfloat16* Wc_p  = Wu_p + HID * DU;                // 128*256

    prep_all<<<HID + (DU * HID + DC * HID) / 256, 256, 0, stream>>>(
        Wl, bl, Wr, Wo, bo, Wu, Wc, Wlo_p, Wro_p, b2, Wu_p, Wc_p, gcur);

    fused_main<<<NBA + NT_C + NT_U, 256, 0, stream>>>(
        xc, Wc_p, bc, Wro_p, b2, out, xu, Wu_p, bu, Wlo_p, pu, esrc, edst, gcur, bke);

    bucket_gather<<<NBUCK, 1024, 0, stream>>>(gcur, bke, (const unsigned int*)pu, out);
}